// Round 24
// baseline (86.724 us; speedup 1.0000x reference)
//
#include <hip/hip_runtime.h>

typedef __bf16 bf16x8 __attribute__((ext_vector_type(8)));
typedef float f32x4 __attribute__((ext_vector_type(4)));

#define GLDS(gp, lp) __builtin_amdgcn_global_load_lds( \
    (const __attribute__((address_space(1))) void*)(gp), \
    (__attribute__((address_space(3))) void*)(lp), 16, 0, 0)
#define WAITV(n) asm volatile("s_waitcnt vmcnt(" #n ")" ::: "memory")
#define MEMF() asm volatile("" ::: "memory")

__device__ __forceinline__ unsigned short f2bf(float f) {
    unsigned int u = __builtin_bit_cast(unsigned int, f);
    u += 0x7fffu + ((u >> 16) & 1u);
    return (unsigned short)(u >> 16);
}

// ---- K1: fused pack (R22 exact). 0..255 packx (8 h-rows), 256..383 packw, 384..513 border.
__global__ __launch_bounds__(512) void k_pack(const float* __restrict__ x,
                                              const float* __restrict__ style,
                                              const float* __restrict__ aw,
                                              const float* __restrict__ ab,
                                              const float* __restrict__ wsrc,
                                              unsigned short* __restrict__ xmod,
                                              unsigned short* __restrict__ wpk3) {
    __shared__ __attribute__((aligned(16))) unsigned char shraw[36864];
    int bid = blockIdx.x, t = threadIdx.x;
    if (bid < 256) {
        unsigned short (*tile)[72] = (unsigned short(*)[72])shraw;
        float* st   = (float*)(shraw + 9728);
        float* s_sh = (float*)(shraw + 11776);
        int ix = bid & 7, hg = (bid >> 3) & 7, b = bid >> 6;
        int i0 = ix << 6;
        st[t] = style[(b << 9) + t];
        __syncthreads();
        {
            int row = t >> 3, seg = t & 7;
            const float4* ap4 = (const float4*)(aw + (size_t)(i0 + row) * 512 + (seg << 6));
            float acc = 0.f;
#pragma unroll
            for (int k = 0; k < 16; ++k) {
                float4 v = ap4[k];
                int e = (seg << 6) + (k << 2);
                acc += v.x * st[e] + v.y * st[e + 1] + v.z * st[e + 2] + v.w * st[e + 3];
            }
            acc += __shfl_xor(acc, 1);
            acc += __shfl_xor(acc, 2);
            acc += __shfl_xor(acc, 4);
            if (seg == 0) {
                float s = acc * 0.04419417382415922f + ab[i0 + row];
                s_sh[row] = s * 0.014731391274719739f;
            }
        }
        __syncthreads();
        int wq = t & 15, chh = t >> 4;
        int ib = (t & 7) << 3, wb = t >> 3;
#pragma unroll 1
        for (int hh = 0; hh < 8; ++hh) {
            int h = (hg << 3) + hh;
#pragma unroll
            for (int p = 0; p < 2; ++p) {
                int il = (p << 5) + chh;
                int i = i0 + il;
                float4 v = *(const float4*)(x + (size_t)((((b << 9) + i) << 6) + h) * 64 + (wq << 2));
                float s = s_sh[il];
                union { unsigned short us[4]; uint2 u2; } u;
                u.us[0] = f2bf(v.x * s); u.us[1] = f2bf(v.y * s);
                u.us[2] = f2bf(v.z * s); u.us[3] = f2bf(v.w * s);
                *(uint2*)&tile[il][wq << 2] = u.u2;
            }
            __syncthreads();
            union { unsigned short us[8]; uint4 v; } u;
#pragma unroll
            for (int j = 0; j < 8; ++j) u.us[j] = tile[ib + j][wb];
            *(uint4*)(xmod + (((size_t)(b * 66 + h + 1) * 66 + (wb + 1)) << 9) + i0 + ib) = u.v;
            __syncthreads();
        }
    } else if (bid < 384) {
        unsigned short* stg = (unsigned short*)shraw;
        int blk = bid - 256;
        int mt = blk >> 5, rem = blk & 31, ic = rem >> 1, half = rem & 1;
        int o_l = t >> 3, c8 = t & 7;
        const float4* src4 = (const float4*)(wsrc + (size_t)((mt << 7) + (half << 6) + o_l) * 4608 + ic * 288);
        int wsl = o_l >> 4, lm = o_l & 15;
#pragma unroll
        for (int q = 0; q < 9; ++q) {
            float4 v = src4[c8 + (q << 3)];
            int e0 = (c8 + (q << 3)) << 2;
#pragma unroll
            for (int c = 0; c < 4; ++c) {
                int e = e0 + c;
                int il = e / 9, r = e - il * 9;
                int lk = il >> 3, j = il & 7;
                float fv = (c == 0) ? v.x : (c == 1) ? v.y : (c == 2) ? v.z : v.w;
                stg[r * 2048 + wsl * 512 + ((lk << 4) + lm) * 8 + j] = f2bf(fv);
            }
        }
        __syncthreads();
        unsigned short* dst = wpk3 + (((size_t)(mt * 144 + ic * 9)) << 12) + (half << 11);
#pragma unroll
        for (int q5 = 0; q5 < 5; ++q5) {
            int v = (q5 << 9) + t;
            if (v < 2304) {
                int q = v >> 8, word = v & 255;
                *(uint4*)(dst + (q << 12) + word * 8) = *(const uint4*)(stg + v * 8);
            }
        }
    } else {
        int idx = (bid - 384) * 512 + t;
        int cell = idx >> 6, sub = idx & 63;
        int b = cell / 260, c = cell - b * 260;
        int row, col;
        if (c < 66)       { row = 0;  col = c; }
        else if (c < 132) { row = 65; col = c - 66; }
        else { int d = c - 132; row = 1 + (d >> 1); col = (d & 1) * 65; }
        uint4 z; z.x = z.y = z.z = z.w = 0u;
        *(uint4*)(xmod + (((size_t)(b * 66 + row) * 66 + col) << 9) + (sub << 3)) = z;
    }
}

// ---- k_conv: R19 base + QUAD-INTERLEAVED step (AITER-style fine MFMA<->load mix).
// Same barriers/vmcnt as R19 (one WAITV(4)+barrier per chunk). Step body = 4 pinned
// segments: {mem batch -> 4 MFMA}. Memory issues while matrix pipe chews prior quad.
__global__ __launch_bounds__(256, 2) void k_conv(const unsigned short* __restrict__ xmod,
                                                 const unsigned short* __restrict__ wpk3,
                                                 float* __restrict__ out) {
    __shared__ __attribute__((aligned(128))) unsigned char lds[2][17408];

    int bid = blockIdx.x;
    int swz = ((bid & 7) << 6) | (bid >> 3);
    int mt = swz >> 7, nt = swz & 127;
    int b = nt >> 5, h0 = (nt & 31) << 1;
    int m0 = mt << 7;
    int tid = threadIdx.x;
    int lane = tid & 63;
    int wv = tid >> 6;
    int wave_m = wv & 1, wave_n = wv >> 1;
    int lm = lane & 15, lk = lane >> 4;

    const unsigned char* xq = (const unsigned char*)xmod;

    int bsrc[5];
#pragma unroll
    for (int q = 0; q < 5; ++q) {
        int c = q * 256 + tid; if (c > 1055) c = 1055;
        int cl = c >> 2, sub = c & 3;
        int row = cl / 66, col = cl - row * 66;
        int sub2 = sub ^ ((col >> 1) & 3);
        bsrc[q] = ((b * 66 + h0 + row) * 66 + col) * 1024 + (sub2 << 4);
    }

    int boff[4][3];
#pragma unroll
    for (int fn = 0; fn < 4; ++fn) {
        int nl = (wave_n << 6) + (fn << 4) + lm;
        int hl = nl >> 6, w = nl & 63;
#pragma unroll
        for (int kw = 0; kw < 3; ++kw) {
            int col = w + kw;
            boff[fn][kw] = hl * 4224 + col * 64 + ((lk ^ ((col >> 1) & 3)) << 4);
        }
    }

    const unsigned short* abase = wpk3 + ((size_t)mt * 144) * 4096 + ((wave_m << 2) << 9) + (lane << 3);

    f32x4 acc[4][4] = {};
    bf16x8 af[3][4];
    bf16x8 bfr[2][4];

    {
        unsigned char* bd = &lds[0][0] + wv * 1024;
        GLDS(xq + bsrc[0], bd);
        GLDS(xq + bsrc[1], bd + 4096);
        GLDS(xq + bsrc[2], bd + 8192);
        GLDS(xq + bsrc[3], bd + 12288);
        if (wv == 0) GLDS(xq + bsrc[4], &lds[0][0] + 16384);
    }
#pragma unroll
    for (int s = 0; s < 2; ++s)
#pragma unroll
        for (int fm = 0; fm < 4; ++fm)
            af[s][fm] = *(const bf16x8*)(abase + s * 4096 + fm * 512);

#pragma unroll 1
    for (int ic = 0; ic < 16; ++ic) {
        const unsigned char* Bb = &lds[ic & 1][0];
        unsigned char* Bn = &lds[(ic + 1) & 1][0];
#pragma unroll
        for (int r = 0; r < 9; ++r) {
            if (r == 0) {
                WAITV(4);
                __builtin_amdgcn_s_barrier();
                MEMF();
#pragma unroll
                for (int fn = 0; fn < 4; ++fn)
                    bfr[0][fn] = *(const bf16x8*)(Bb + boff[fn][0]);
                MEMF();
            }
            int s = ic * 9 + r;
            const unsigned short* ap = abase + (size_t)(s + 2) * 4096;
            const int cur3 = r % 3, pre3 = (r + 2) % 3;
            const int curb = r & 1, nxtb = curb ^ 1;
            int r1 = r + 1;
            int kh1 = r1 / 3, kw1 = r1 - kh1 * 3;     // only used when r<8

            __builtin_amdgcn_s_setprio(1);
            // ---- segment 0: af(s+2) pair 0,1 -> 4 MFMA (fm 0) ----
            af[pre3][0] = *(const bf16x8*)(ap);
            af[pre3][1] = *(const bf16x8*)(ap + 512);
            MEMF();
#pragma unroll
            for (int fn = 0; fn < 4; ++fn)
                acc[0][fn] = __builtin_amdgcn_mfma_f32_16x16x32_bf16(af[cur3][0], bfr[curb][fn], acc[0][fn], 0, 0, 0);
            MEMF();
            // ---- segment 1: af(s+2) pair 2,3 -> 4 MFMA (fm 1) ----
            af[pre3][2] = *(const bf16x8*)(ap + 1024);
            af[pre3][3] = *(const bf16x8*)(ap + 1536);
            MEMF();
#pragma unroll
            for (int fn = 0; fn < 4; ++fn)
                acc[1][fn] = __builtin_amdgcn_mfma_f32_16x16x32_bf16(af[cur3][1], bfr[curb][fn], acc[1][fn], 0, 0, 0);
            MEMF();
            // ---- segment 2: bfr(s+1) fn 0,1 (+ B-GLDS batch at r==4) -> 4 MFMA (fm 2) ----
            if (r == 4) {
                int icb = (ic + 1) << 6;
                unsigned char* bd = Bn + wv * 1024;
                GLDS(xq + bsrc[0] + icb, bd);
                GLDS(xq + bsrc[1] + icb, bd + 4096);
                GLDS(xq + bsrc[2] + icb, bd + 8192);
                GLDS(xq + bsrc[3] + icb, bd + 12288);
                if (wv == 0) GLDS(xq + bsrc[4] + icb, Bn + 16384);
            }
            if (r < 8) {
                bfr[nxtb][0] = *(const bf16x8*)(Bb + boff[0][kw1] + kh1 * 4224);
                bfr[nxtb][1] = *(const bf16x8*)(Bb + boff[1][kw1] + kh1 * 4224);
            }
            MEMF();
#pragma unroll
            for (int fn = 0; fn < 4; ++fn)
                acc[2][fn] = __builtin_amdgcn_mfma_f32_16x16x32_bf16(af[cur3][2], bfr[curb][fn], acc[2][fn], 0, 0, 0);
            MEMF();
            // ---- segment 3: bfr(s+1) fn 2,3 -> 4 MFMA (fm 3) ----
            if (r < 8) {
                bfr[nxtb][2] = *(const bf16x8*)(Bb + boff[2][kw1] + kh1 * 4224);
                bfr[nxtb][3] = *(const bf16x8*)(Bb + boff[3][kw1] + kh1 * 4224);
            }
            MEMF();
#pragma unroll
            for (int fn = 0; fn < 4; ++fn)
                acc[3][fn] = __builtin_amdgcn_mfma_f32_16x16x32_bf16(af[cur3][3], bfr[curb][fn], acc[3][fn], 0, 0, 0);
            __builtin_amdgcn_s_setprio(0);
            MEMF();
        }
    }

#pragma unroll
    for (int fm = 0; fm < 4; ++fm) {
        int o = m0 + (wave_m << 6) + (fm << 4) + (lk << 2);
#pragma unroll
        for (int fn = 0; fn < 4; ++fn) {
            int nl = (wave_n << 6) + (fn << 4) + lm;
            int hl = nl >> 6, w = nl & 63;
            float* dst = out + ((((b << 9) + o) << 6) + (h0 + hl)) * 64 + w;
#pragma unroll
            for (int rr = 0; rr < 4; ++rr)
                dst[rr * 4096] = acc[fm][fn][rr];
        }
    }
}

extern "C" void kernel_launch(void* const* d_in, const int* in_sizes, int n_in,
                              void* d_out, int out_size, void* d_ws, size_t ws_size,
                              hipStream_t stream) {
    const float* x      = (const float*)d_in[0];
    const float* style  = (const float*)d_in[1];
    const float* weight = (const float*)d_in[2];
    const float* aff_w  = (const float*)d_in[3];
    const float* aff_b  = (const float*)d_in[4];
    float* out = (float*)d_out;

    unsigned short* xmod = (unsigned short*)d_ws;            // 17,842,176 B
    unsigned short* wpk3 = xmod + 8921088;                   // 4,718,592 B (+16KB tail slack)

    hipLaunchKernelGGL(k_pack, dim3(514), dim3(512), 0, stream,
                       x, style, aff_w, aff_b, weight, xmod, wpk3);
    hipLaunchKernelGGL(k_conv, dim3(512), dim3(256), 0, stream, xmod, wpk3, out);
}